// Round 4
// baseline (1398.123 us; speedup 1.0000x reference)
//
#include <hip/hip_runtime.h>

#define HID 128
#define PROW 104   // P row: src-half at [0..49], dst-half at [52..101]
#define KC 16      // K-chunk of the pipelined edge GEMM
#define NKC 8      // 128/KC

// ---------- detect int32 vs int64 edge_index layout ----------
__global__ void detect_idx_kernel(const unsigned int* __restrict__ p, int* __restrict__ flag) {
  __shared__ int s;
  if (threadIdx.x == 0) s = 0;
  __syncthreads();
  if (p[2 * threadIdx.x + 1] != 0u) atomicOr(&s, 1);
  __syncthreads();
  if (threadIdx.x == 0) *flag = s;   // 1 -> int32 layout, 0 -> int64 layout
}

// ---------- node precompute: P[n][half*52+j] = relu(x[n]) @ W1[half*128 .. +127][j] ----------
__global__ __launch_bounds__(256, 4)
void node_pre_kernel(const float* __restrict__ x, const float* __restrict__ W1,
                     float* __restrict__ P, int n_nodes) {
  __shared__ __align__(16) float a_s[32][132];
  __shared__ __align__(16) float w_s[32][64];
  const int t = threadIdx.x;
  const int half = blockIdx.y;
  const int n0 = blockIdx.x * 128;
  const int jt = t & 15, rt = t >> 4;
  float acc[8][4];
#pragma unroll
  for (int i = 0; i < 8; ++i)
#pragma unroll
    for (int q = 0; q < 4; ++q) acc[i][q] = 0.f;

  for (int kc = 0; kc < 4; ++kc) {
#pragma unroll
    for (int i = 0; i < 4; ++i) {
      int f = t + 256 * i;
      int e = f >> 3;
      int k4 = (f & 7) << 2;
      int n = n0 + e;
      float4 v = make_float4(0.f, 0.f, 0.f, 0.f);
      if (n < n_nodes) v = *(const float4*)&x[(long)n * HID + kc * 32 + k4];
      a_s[k4 + 0][e] = fmaxf(v.x, 0.f);
      a_s[k4 + 1][e] = fmaxf(v.y, 0.f);
      a_s[k4 + 2][e] = fmaxf(v.z, 0.f);
      a_s[k4 + 3][e] = fmaxf(v.w, 0.f);
    }
#pragma unroll
    for (int i = 0; i < 8; ++i) {
      int f = t + 256 * i;
      int k = f >> 6, j = f & 63;
      float w = 0.f;
      if (j < 50) w = W1[(half * 128 + kc * 32 + k) * 50 + j];
      w_s[k][j] = w;
    }
    __syncthreads();
#pragma unroll 8
    for (int kk = 0; kk < 32; ++kk) {
      float4 w4 = *(const float4*)&w_s[kk][jt * 4];
      float4 a0 = *(const float4*)&a_s[kk][rt * 8];
      float4 a1 = *(const float4*)&a_s[kk][rt * 8 + 4];
      float av[8] = {a0.x, a0.y, a0.z, a0.w, a1.x, a1.y, a1.z, a1.w};
      float wv[4] = {w4.x, w4.y, w4.z, w4.w};
#pragma unroll
      for (int ri = 0; ri < 8; ++ri)
#pragma unroll
        for (int q = 0; q < 4; ++q) acc[ri][q] = fmaf(av[ri], wv[q], acc[ri][q]);
    }
    __syncthreads();
  }
  int jb = jt * 4;
  if (jb < 50) {
#pragma unroll
    for (int ri = 0; ri < 8; ++ri) {
      int n = n0 + rt * 8 + ri;
      if (n < n_nodes) {
#pragma unroll
        for (int q = 0; q < 4; ++q) {
          int j = jb + q;
          if (j < 50) P[(long)n * PROW + half * 52 + j] = acc[ri][q];
        }
      }
    }
  }
}

// ---------- fused edge kernel: pipelined ea@W1c + gather(P) + MLP layers 2,3 ----------
__global__ __launch_bounds__(256, 4)
void edge_kernel(const float* __restrict__ ea, const void* __restrict__ eidx,
                 const float* __restrict__ W1, const float* __restrict__ b1,
                 const float* __restrict__ W2, const float* __restrict__ b2,
                 const float* __restrict__ W3, const float* __restrict__ b3,
                 const float* __restrict__ P, const int* __restrict__ flag,
                 float* __restrict__ out, int n_edges) {
  // double-buffered GEMM tiles union h1 (h1 only live after GEMM completes)
  __shared__ __align__(16) union SU {
    struct {
      float a[2][KC][132];   // 16896 B, transposed [k][edge]
      float w[2][KC][64];    // 8192 B
    } g;
    float h1[128][51];       // 26112 B (stride 51: bank-coprime)
  } u;
  __shared__ float w2_s[50][25];
  __shared__ float w3_s[25];
  __shared__ float b1_s[64];
  __shared__ float b2_s[25];
  __shared__ float p_s[2][128];
  __shared__ int src_s[128], dst_s[128];

  const int t = threadIdx.x;
  const int e0 = blockIdx.x * 128;
  const int jt = t & 15, rt = t >> 4;
  const int wj = (jt <= 12) ? jt * 4 : 48;   // clamped W col (lanes 13..15 duplicate, writes guarded)

  // ---- prologue: small cooperative loads ----
  for (int f = t; f < 1250; f += 256) ((float*)w2_s)[f] = W2[f];
  if (t < 25) { w3_s[t] = W3[t]; b2_s[t] = b2[t]; }
  if (t < 64) b1_s[t] = (t < 50) ? b1[t] : 0.f;
  const int use32 = *flag;
  if (t < 128) {
    int e = e0 + t;
    int v = 0;
    if (e < n_edges) v = use32 ? ((const int*)eidx)[e] : (int)((const long long*)eidx)[e];
    src_s[t] = v;
  } else {
    int e = e0 + (t - 128);
    int v = 0;
    if (e < n_edges)
      v = use32 ? ((const int*)eidx)[(long)n_edges + e] : (int)((const long long*)eidx)[(long)n_edges + e];
    dst_s[t - 128] = v;
  }

  // staging addressing
  const int le = t >> 2;             // 0..63 (edge-within-half)
  const int k4 = (t & 3) << 2;       // 0,4,8,12 (k-within-chunk)
  const int wjj = t & 63;            // W col for staging
  const int wk0 = t >> 6;            // W k base (0..3), rows wk0+4i

  float4 apf[2];
  float  wpf[4];

  // chunk 0 -> regs
#pragma unroll
  for (int i = 0; i < 2; ++i) {
    int ee = e0 + le + 64 * i;
    apf[i] = make_float4(0.f, 0.f, 0.f, 0.f);
    if (ee < n_edges) apf[i] = *(const float4*)&ea[(long)ee * HID + k4];
  }
#pragma unroll
  for (int i = 0; i < 4; ++i)
    wpf[i] = (wjj < 50) ? W1[(256 + wk0 + 4 * i) * 50 + wjj] : 0.f;
  // store chunk 0 -> LDS buf0
#pragma unroll
  for (int i = 0; i < 2; ++i) {
    int e = le + 64 * i;
    u.g.a[0][k4 + 0][e] = apf[i].x;
    u.g.a[0][k4 + 1][e] = apf[i].y;
    u.g.a[0][k4 + 2][e] = apf[i].z;
    u.g.a[0][k4 + 3][e] = apf[i].w;
  }
#pragma unroll
  for (int i = 0; i < 4; ++i) u.g.w[0][wk0 + 4 * i][wjj] = wpf[i];
  // issue chunk 1 loads
#pragma unroll
  for (int i = 0; i < 2; ++i) {
    int ee = e0 + le + 64 * i;
    float4 v = make_float4(0.f, 0.f, 0.f, 0.f);
    if (ee < n_edges) v = *(const float4*)&ea[(long)ee * HID + KC + k4];
    apf[i] = v;
  }
#pragma unroll
  for (int i = 0; i < 4; ++i)
    wpf[i] = (wjj < 50) ? W1[(256 + KC + wk0 + 4 * i) * 50 + wjj] : 0.f;
  __syncthreads();

  // ---- pipelined GEMM: compute kc | store kc+1 | issue kc+2 | barrier ----
  float acc[8][4];
#pragma unroll
  for (int i = 0; i < 8; ++i)
#pragma unroll
    for (int q = 0; q < 4; ++q) acc[i][q] = 0.f;

  for (int kc = 0; kc < NKC; ++kc) {
    const int cur = kc & 1;
#pragma unroll
    for (int kk = 0; kk < KC; ++kk) {
      float4 w4 = *(const float4*)&u.g.w[cur][kk][wj];
      float4 a0 = *(const float4*)&u.g.a[cur][kk][rt * 8];
      float4 a1 = *(const float4*)&u.g.a[cur][kk][rt * 8 + 4];
      float avv[8] = {a0.x, a0.y, a0.z, a0.w, a1.x, a1.y, a1.z, a1.w};
      float wv[4] = {w4.x, w4.y, w4.z, w4.w};
#pragma unroll
      for (int ri = 0; ri < 8; ++ri)
#pragma unroll
        for (int q = 0; q < 4; ++q) acc[ri][q] = fmaf(avv[ri], wv[q], acc[ri][q]);
    }
    if (kc < NKC - 1) {
      const int nxt = cur ^ 1;
#pragma unroll
      for (int i = 0; i < 2; ++i) {
        int e = le + 64 * i;
        u.g.a[nxt][k4 + 0][e] = apf[i].x;
        u.g.a[nxt][k4 + 1][e] = apf[i].y;
        u.g.a[nxt][k4 + 2][e] = apf[i].z;
        u.g.a[nxt][k4 + 3][e] = apf[i].w;
      }
#pragma unroll
      for (int i = 0; i < 4; ++i) u.g.w[nxt][wk0 + 4 * i][wjj] = wpf[i];
      if (kc < NKC - 2) {
#pragma unroll
        for (int i = 0; i < 2; ++i) {
          int ee = e0 + le + 64 * i;
          float4 v = make_float4(0.f, 0.f, 0.f, 0.f);
          if (ee < n_edges) v = *(const float4*)&ea[(long)ee * HID + (kc + 2) * KC + k4];
          apf[i] = v;
        }
#pragma unroll
        for (int i = 0; i < 4; ++i)
          wpf[i] = (wjj < 50) ? W1[(256 + (kc + 2) * KC + wk0 + 4 * i) * 50 + wjj] : 0.f;
      }
    }
    __syncthreads();
  }

  // ---- layer-1 epilogue: direct P gather + bias + relu -> h1 (union safe after final barrier) ----
  const int jb = jt * 4;
  if (jb < 50) {
#pragma unroll
    for (int ri = 0; ri < 8; ++ri) {
      int e = rt * 8 + ri;
      long s = src_s[e], d = dst_s[e];
      float4 pa = *(const float4*)&P[s * PROW + jb];
      float4 pb = *(const float4*)&P[d * PROW + 52 + jb];
      float par[4] = {pa.x, pa.y, pa.z, pa.w};
      float pbr[4] = {pb.x, pb.y, pb.z, pb.w};
#pragma unroll
      for (int q = 0; q < 4; ++q) {
        int j = jb + q;
        if (j < 50) {
          float v = acc[ri][q] + par[q] + pbr[q] + b1_s[j];
          u.h1[e][j] = fmaxf(v, 0.f);
        }
      }
    }
  }
  __syncthreads();

  // ---- layers 2 + 3: two threads per edge, 13/12 columns each ----
  const int e2 = t & 127, hh = t >> 7;
  const int jb2 = hh * 13;
  float acc2[13];
#pragma unroll
  for (int jj = 0; jj < 13; ++jj) {
    int j2 = jb2 + jj;
    acc2[jj] = (j2 < 25) ? b2_s[j2] : 0.f;
  }
  for (int k2 = 0; k2 < 50; ++k2) {
    float v = u.h1[e2][k2];
#pragma unroll
    for (int jj = 0; jj < 13; ++jj) {
      int j2 = jb2 + jj;
      if (j2 < 25) acc2[jj] = fmaf(v, w2_s[k2][j2], acc2[jj]);
    }
  }
  float part = 0.f;
#pragma unroll
  for (int jj = 0; jj < 13; ++jj) {
    int j2 = jb2 + jj;
    if (j2 < 25) part += fmaxf(acc2[jj], 0.f) * w3_s[j2];
  }
  p_s[hh][e2] = part;
  __syncthreads();
  if (t < 128 && (e0 + t) < n_edges) out[e0 + t] = p_s[0][t] + p_s[1][t] + b3[0];
}

// ---------- naive fallback (only if ws too small for P) ----------
__global__ __launch_bounds__(256, 2)
void edge_naive_kernel(const float* __restrict__ x, const float* __restrict__ ea,
                       const void* __restrict__ eidx,
                       const float* __restrict__ W1, const float* __restrict__ b1,
                       const float* __restrict__ W2, const float* __restrict__ b2,
                       const float* __restrict__ W3, const float* __restrict__ b3,
                       const int* __restrict__ flag, int use32_const,
                       float* __restrict__ out, int n_edges) {
  int e = blockIdx.x * blockDim.x + threadIdx.x;
  if (e >= n_edges) return;
  int use32 = flag ? *flag : use32_const;
  long s, d;
  if (use32) {
    s = ((const int*)eidx)[e];
    d = ((const int*)eidx)[(long)n_edges + e];
  } else {
    s = (long)((const long long*)eidx)[e];
    d = (long)((const long long*)eidx)[(long)n_edges + e];
  }
  float h1[50];
#pragma unroll
  for (int j = 0; j < 50; ++j) h1[j] = b1[j];
  for (int k = 0; k < 128; ++k) {
    float v = fmaxf(x[s * HID + k], 0.f);
#pragma unroll
    for (int j = 0; j < 50; ++j) h1[j] = fmaf(v, W1[k * 50 + j], h1[j]);
  }
  for (int k = 0; k < 128; ++k) {
    float v = fmaxf(x[d * HID + k], 0.f);
#pragma unroll
    for (int j = 0; j < 50; ++j) h1[j] = fmaf(v, W1[(128 + k) * 50 + j], h1[j]);
  }
  for (int k = 0; k < 128; ++k) {
    float v = ea[(long)e * HID + k];
#pragma unroll
    for (int j = 0; j < 50; ++j) h1[j] = fmaf(v, W1[(256 + k) * 50 + j], h1[j]);
  }
  float o = b3[0];
  for (int j2 = 0; j2 < 25; ++j2) {
    float h2 = b2[j2];
#pragma unroll 10
    for (int k = 0; k < 50; ++k) h2 = fmaf(fmaxf(h1[k], 0.f), W2[k * 25 + j2], h2);
    o = fmaf(fmaxf(h2, 0.f), W3[j2], o);
  }
  out[e] = o;
}

extern "C" void kernel_launch(void* const* d_in, const int* in_sizes, int n_in,
                              void* d_out, int out_size, void* d_ws, size_t ws_size,
                              hipStream_t stream) {
  const float* x  = (const float*)d_in[0];
  const float* ea = (const float*)d_in[1];
  const void*  ei = d_in[2];
  const float* W1 = (const float*)d_in[3];
  const float* b1 = (const float*)d_in[4];
  const float* W2 = (const float*)d_in[5];
  const float* b2 = (const float*)d_in[6];
  const float* W3 = (const float*)d_in[7];
  const float* b3 = (const float*)d_in[8];
  float* out = (float*)d_out;
  const int n_nodes = in_sizes[0] / HID;
  const int n_edges = in_sizes[1] / HID;
  const size_t pbytes = (size_t)n_nodes * PROW * sizeof(float);

  if (ws_size >= pbytes + sizeof(int)) {
    float* P = (float*)d_ws;
    int* flag = (int*)((char*)d_ws + pbytes);
    hipLaunchKernelGGL(detect_idx_kernel, dim3(1), dim3(256), 0, stream,
                       (const unsigned int*)ei, flag);
    dim3 gp((n_nodes + 127) / 128, 2);
    hipLaunchKernelGGL(node_pre_kernel, gp, dim3(256), 0, stream, x, W1, P, n_nodes);
    dim3 ge((n_edges + 127) / 128);
    hipLaunchKernelGGL(edge_kernel, ge, dim3(256), 0, stream,
                       ea, ei, W1, b1, W2, b2, W3, b3, P, flag, out, n_edges);
  } else if (ws_size >= sizeof(int)) {
    int* flag = (int*)d_ws;
    hipLaunchKernelGGL(detect_idx_kernel, dim3(1), dim3(256), 0, stream,
                       (const unsigned int*)ei, flag);
    hipLaunchKernelGGL(edge_naive_kernel, dim3((n_edges + 255) / 256), dim3(256), 0, stream,
                       x, ea, ei, W1, b1, W2, b2, W3, b3, flag, 1, out, n_edges);
  } else {
    hipLaunchKernelGGL(edge_naive_kernel, dim3((n_edges + 255) / 256), dim3(256), 0, stream,
                       x, ea, ei, W1, b1, W2, b2, W3, b3, (const int*)nullptr, 1, out, n_edges);
  }
}

// Round 5
// 355.149 us; speedup vs baseline: 3.9367x; 3.9367x over previous
//
#include <hip/hip_runtime.h>

#define HID 128
#define PROW 104   // P row: src-half at [0..49], dst-half at [52..101]
#define KC 16      // K-chunk of the pipelined edge GEMM
#define NKC 8      // 128/KC

// direct global->LDS DMA, 16B per lane (dest = wave-uniform base + lane*16)
__device__ __forceinline__ void gload16(const void* g, void* l) {
  __builtin_amdgcn_global_load_lds((const __attribute__((address_space(1))) void*)g,
                                   (__attribute__((address_space(3))) void*)l, 16, 0, 0);
}

// ---------- detect int32 vs int64 edge_index layout ----------
__global__ void detect_idx_kernel(const unsigned int* __restrict__ p, int* __restrict__ flag) {
  __shared__ int s;
  if (threadIdx.x == 0) s = 0;
  __syncthreads();
  if (p[2 * threadIdx.x + 1] != 0u) atomicOr(&s, 1);
  __syncthreads();
  if (threadIdx.x == 0) *flag = s;   // 1 -> int32 layout, 0 -> int64 layout
}

// ---------- node precompute: P[n][half*52+j] = relu(x[n]) @ W1[half*128 .. +127][j] ----------
__global__ __launch_bounds__(256, 4)
void node_pre_kernel(const float* __restrict__ x, const float* __restrict__ W1,
                     float* __restrict__ P, int n_nodes) {
  __shared__ __align__(16) float a_s[32][132];
  __shared__ __align__(16) float w_s[32][64];
  const int t = threadIdx.x;
  const int half = blockIdx.y;
  const int n0 = blockIdx.x * 128;
  const int jt = t & 15, rt = t >> 4;
  float acc[8][4];
#pragma unroll
  for (int i = 0; i < 8; ++i)
#pragma unroll
    for (int q = 0; q < 4; ++q) acc[i][q] = 0.f;

  for (int kc = 0; kc < 4; ++kc) {
#pragma unroll
    for (int i = 0; i < 4; ++i) {
      int f = t + 256 * i;
      int e = f >> 3;
      int k4 = (f & 7) << 2;
      int n = n0 + e;
      float4 v = make_float4(0.f, 0.f, 0.f, 0.f);
      if (n < n_nodes) v = *(const float4*)&x[(long)n * HID + kc * 32 + k4];
      a_s[k4 + 0][e] = fmaxf(v.x, 0.f);
      a_s[k4 + 1][e] = fmaxf(v.y, 0.f);
      a_s[k4 + 2][e] = fmaxf(v.z, 0.f);
      a_s[k4 + 3][e] = fmaxf(v.w, 0.f);
    }
#pragma unroll
    for (int i = 0; i < 8; ++i) {
      int f = t + 256 * i;
      int k = f >> 6, j = f & 63;
      float w = 0.f;
      if (j < 50) w = W1[(half * 128 + kc * 32 + k) * 50 + j];
      w_s[k][j] = w;
    }
    __syncthreads();
#pragma unroll 8
    for (int kk = 0; kk < 32; ++kk) {
      float4 w4 = *(const float4*)&w_s[kk][jt * 4];
      float4 a0 = *(const float4*)&a_s[kk][rt * 8];
      float4 a1 = *(const float4*)&a_s[kk][rt * 8 + 4];
      float av[8] = {a0.x, a0.y, a0.z, a0.w, a1.x, a1.y, a1.z, a1.w};
      float wv[4] = {w4.x, w4.y, w4.z, w4.w};
#pragma unroll
      for (int ri = 0; ri < 8; ++ri)
#pragma unroll
        for (int q = 0; q < 4; ++q) acc[ri][q] = fmaf(av[ri], wv[q], acc[ri][q]);
    }
    __syncthreads();
  }
  int jb = jt * 4;
  if (jb < 50) {
#pragma unroll
    for (int ri = 0; ri < 8; ++ri) {
      int n = n0 + rt * 8 + ri;
      if (n < n_nodes) {
#pragma unroll
        for (int q = 0; q < 4; ++q) {
          int j = jb + q;
          if (j < 50) P[(long)n * PROW + half * 52 + j] = acc[ri][q];
        }
      }
    }
  }
}

// ---------- fused edge kernel: gload_lds-pipelined ea@W1c + gather(P) + MLP layers 2,3 ----------
__global__ __launch_bounds__(256, 2)
void edge_kernel(const float* __restrict__ ea, const void* __restrict__ eidx,
                 const float* __restrict__ W1, const float* __restrict__ b1,
                 const float* __restrict__ W2, const float* __restrict__ b2,
                 const float* __restrict__ W3, const float* __restrict__ b3,
                 const float* __restrict__ P, const int* __restrict__ flag,
                 float* __restrict__ out, int n_edges) {
  __shared__ __align__(16) union WU {
    float w[128][52];    // W1c staged once (26.6 KB), live during GEMM
    float h1[128][51];   // layer-1 output, live after GEMM
  } u;
  __shared__ __align__(16) float a_s[2][128][KC];  // 2 x 8 KB, [buf][edge][k], linear 64B rows
  __shared__ float w2_s[50][25];
  __shared__ float w3_s[25];
  __shared__ float b1_s[64];
  __shared__ float b2_s[25];
  __shared__ float p_s[2][128];
  __shared__ int src_s[128], dst_s[128];

  const int t = threadIdx.x;
  const int e0 = blockIdx.x * 128;
  const int jt = t & 15, rt = t >> 4;
  const int wj = (jt <= 12) ? jt * 4 : 48;   // clamped W col (lanes 13..15 duplicate, stores guarded)
  const int wv = t >> 6;                     // wave 0..3
  const int ln = t & 63;                     // lane
  const bool full = (e0 + 128 <= n_edges);

  // ---- stage one K-chunk of ea into a_s[buf] ----
  auto stage = [&](int buf, int kc) {
    if (full) {
#pragma unroll
      for (int c = 0; c < 2; ++c) {
        int et = wv * 32 + c * 16 + (ln >> 2);
        gload16(&ea[(long)(e0 + et) * HID + kc * KC + (ln & 3) * 4],
                &a_s[buf][et][(ln & 3) * 4]);
      }
    } else {
      for (int f = t; f < 512; f += 256) {   // 512 float4 = 128 edges x 4 quads
        int et = f >> 2, q = f & 3;
        float4 v = make_float4(0.f, 0.f, 0.f, 0.f);
        if (e0 + et < n_edges) v = *(const float4*)&ea[(long)(e0 + et) * HID + kc * KC + q * 4];
        *(float4*)&a_s[buf][et][q * 4] = v;
      }
    }
  };

  // ---- prologue ----
  for (int f = t; f < 1250; f += 256) ((float*)w2_s)[f] = W2[f];
  if (t < 25) { w3_s[t] = W3[t]; b2_s[t] = b2[t]; }
  if (t < 64) b1_s[t] = (t < 50) ? b1[t] : 0.f;
  const int use32 = *flag;
  if (t < 128) {
    int e = e0 + t;
    int v = 0;
    if (e < n_edges) v = use32 ? ((const int*)eidx)[e] : (int)((const long long*)eidx)[e];
    src_s[t] = v;
  } else {
    int e = e0 + (t - 128);
    int v = 0;
    if (e < n_edges)
      v = use32 ? ((const int*)eidx)[(long)n_edges + e] : (int)((const long long*)eidx)[(long)n_edges + e];
    dst_s[t - 128] = v;
  }
  // stage all of W1c once (rows 256..383 of W1), cols padded 50->52
  for (int f = t; f < 128 * 52; f += 256) {
    int r = f / 52, j = f % 52;
    u.w[r][j] = (j < 50) ? W1[(256 + r) * 50 + j] : 0.f;
  }
  stage(0, 0);
  stage(1, 1);
  __syncthreads();   // drains both DMA chunks + all prologue stores

  // ---- pipelined GEMM: compute(kc) | barrier | issue DMA(kc+2) ----
  float acc[8][4];
#pragma unroll
  for (int i = 0; i < 8; ++i)
#pragma unroll
    for (int q = 0; q < 4; ++q) acc[i][q] = 0.f;

  for (int kc = 0; kc < NKC; ++kc) {
    const int cur = kc & 1;
#pragma unroll
    for (int kq = 0; kq < KC / 4; ++kq) {
      float4 w4[4];
#pragma unroll
      for (int i = 0; i < 4; ++i)
        w4[i] = *(const float4*)&u.w[kc * KC + kq * 4 + i][wj];
#pragma unroll
      for (int ri = 0; ri < 8; ++ri) {
        float4 a4 = *(const float4*)&a_s[cur][rt + 16 * ri][kq * 4];
        float am[4] = {a4.x, a4.y, a4.z, a4.w};
#pragma unroll
        for (int kk = 0; kk < 4; ++kk) {
          acc[ri][0] = fmaf(am[kk], w4[kk].x, acc[ri][0]);
          acc[ri][1] = fmaf(am[kk], w4[kk].y, acc[ri][1]);
          acc[ri][2] = fmaf(am[kk], w4[kk].z, acc[ri][2]);
          acc[ri][3] = fmaf(am[kk], w4[kk].w, acc[ri][3]);
        }
      }
    }
    __syncthreads();                       // all reads of buf[cur] done; chunk kc+1 arrived
    if (kc + 2 < NKC) stage(cur, kc + 2);  // DMA lands during next phase's compute
  }

  // ---- layer-1 epilogue: P gather + bias + relu -> h1 (union over W1c, safe after barrier) ----
  const int jb = jt * 4;
  if (jb < 50) {
#pragma unroll
    for (int ri = 0; ri < 8; ++ri) {
      int e = rt + 16 * ri;
      long s = src_s[e], d = dst_s[e];
      float4 pa = *(const float4*)&P[s * PROW + jb];
      float4 pb = *(const float4*)&P[d * PROW + 52 + jb];
      float par[4] = {pa.x, pa.y, pa.z, pa.w};
      float pbr[4] = {pb.x, pb.y, pb.z, pb.w};
#pragma unroll
      for (int q = 0; q < 4; ++q) {
        int j = jb + q;
        if (j < 50) {
          float v = acc[ri][q] + par[q] + pbr[q] + b1_s[j];
          u.h1[e][j] = fmaxf(v, 0.f);
        }
      }
    }
  }
  __syncthreads();

  // ---- layers 2 + 3: two threads per edge, 13/12 columns each ----
  const int e2 = t & 127, hh = t >> 7;
  const int jb2 = hh * 13;
  float acc2[13];
#pragma unroll
  for (int jj = 0; jj < 13; ++jj) {
    int j2 = jb2 + jj;
    acc2[jj] = (j2 < 25) ? b2_s[j2] : 0.f;
  }
  for (int k2 = 0; k2 < 50; ++k2) {
    float v = u.h1[e2][k2];
#pragma unroll
    for (int jj = 0; jj < 13; ++jj) {
      int j2 = jb2 + jj;
      if (j2 < 25) acc2[jj] = fmaf(v, w2_s[k2][j2], acc2[jj]);
    }
  }
  float part = 0.f;
#pragma unroll
  for (int jj = 0; jj < 13; ++jj) {
    int j2 = jb2 + jj;
    if (j2 < 25) part += fmaxf(acc2[jj], 0.f) * w3_s[j2];
  }
  p_s[hh][e2] = part;
  __syncthreads();
  if (t < 128 && (e0 + t) < n_edges) out[e0 + t] = p_s[0][t] + p_s[1][t] + b3[0];
}

// ---------- naive fallback (only if ws too small for P) ----------
__global__ __launch_bounds__(256, 2)
void edge_naive_kernel(const float* __restrict__ x, const float* __restrict__ ea,
                       const void* __restrict__ eidx,
                       const float* __restrict__ W1, const float* __restrict__ b1,
                       const float* __restrict__ W2, const float* __restrict__ b2,
                       const float* __restrict__ W3, const float* __restrict__ b3,
                       const int* __restrict__ flag, int use32_const,
                       float* __restrict__ out, int n_edges) {
  int e = blockIdx.x * blockDim.x + threadIdx.x;
  if (e >= n_edges) return;
  int use32 = flag ? *flag : use32_const;
  long s, d;
  if (use32) {
    s = ((const int*)eidx)[e];
    d = ((const int*)eidx)[(long)n_edges + e];
  } else {
    s = (long)((const long long*)eidx)[e];
    d = (long)((const long long*)eidx)[(long)n_edges + e];
  }
  float h1[50];
#pragma unroll
  for (int j = 0; j < 50; ++j) h1[j] = b1[j];
  for (int k = 0; k < 128; ++k) {
    float v = fmaxf(x[s * HID + k], 0.f);
#pragma unroll
    for (int j = 0; j < 50; ++j) h1[j] = fmaf(v, W1[k * 50 + j], h1[j]);
  }
  for (int k = 0; k < 128; ++k) {
    float v = fmaxf(x[d * HID + k], 0.f);
#pragma unroll
    for (int j = 0; j < 50; ++j) h1[j] = fmaf(v, W1[(128 + k) * 50 + j], h1[j]);
  }
  for (int k = 0; k < 128; ++k) {
    float v = ea[(long)e * HID + k];
#pragma unroll
    for (int j = 0; j < 50; ++j) h1[j] = fmaf(v, W1[(256 + k) * 50 + j], h1[j]);
  }
  float o = b3[0];
  for (int j2 = 0; j2 < 25; ++j2) {
    float h2 = b2[j2];
#pragma unroll 10
    for (int k = 0; k < 50; ++k) h2 = fmaf(fmaxf(h1[k], 0.f), W2[k * 25 + j2], h2);
    o = fmaf(fmaxf(h2, 0.f), W3[j2], o);
  }
  out[e] = o;
}

extern "C" void kernel_launch(void* const* d_in, const int* in_sizes, int n_in,
                              void* d_out, int out_size, void* d_ws, size_t ws_size,
                              hipStream_t stream) {
  const float* x  = (const float*)d_in[0];
  const float* ea = (const float*)d_in[1];
  const void*  ei = d_in[2];
  const float* W1 = (const float*)d_in[3];
  const float* b1 = (const float*)d_in[4];
  const float* W2 = (const float*)d_in[5];
  const float* b2 = (const float*)d_in[6];
  const float* W3 = (const float*)d_in[7];
  const float* b3 = (const float*)d_in[8];
  float* out = (float*)d_out;
  const int n_nodes = in_sizes[0] / HID;
  const int n_edges = in_sizes[1] / HID;
  const size_t pbytes = (size_t)n_nodes * PROW * sizeof(float);

  if (ws_size >= pbytes + sizeof(int)) {
    float* P = (float*)d_ws;
    int* flag = (int*)((char*)d_ws + pbytes);
    hipLaunchKernelGGL(detect_idx_kernel, dim3(1), dim3(256), 0, stream,
                       (const unsigned int*)ei, flag);
    dim3 gp((n_nodes + 127) / 128, 2);
    hipLaunchKernelGGL(node_pre_kernel, gp, dim3(256), 0, stream, x, W1, P, n_nodes);
    dim3 ge((n_edges + 127) / 128);
    hipLaunchKernelGGL(edge_kernel, ge, dim3(256), 0, stream,
                       ea, ei, W1, b1, W2, b2, W3, b3, P, flag, out, n_edges);
  } else if (ws_size >= sizeof(int)) {
    int* flag = (int*)d_ws;
    hipLaunchKernelGGL(detect_idx_kernel, dim3(1), dim3(256), 0, stream,
                       (const unsigned int*)ei, flag);
    hipLaunchKernelGGL(edge_naive_kernel, dim3((n_edges + 255) / 256), dim3(256), 0, stream,
                       x, ea, ei, W1, b1, W2, b2, W3, b3, flag, 1, out, n_edges);
  } else {
    hipLaunchKernelGGL(edge_naive_kernel, dim3((n_edges + 255) / 256), dim3(256), 0, stream,
                       x, ea, ei, W1, b1, W2, b2, W3, b3, (const int*)nullptr, 1, out, n_edges);
  }
}